// Round 2
// baseline (400.798 us; speedup 1.0000x reference)
//
#include <hip/hip_runtime.h>
#include <cstdint>
#include <cstddef>

#define T_TOKENS 8192
#define K_DIM 4096
#define N_DIM 4096

#define PACK_BLOCKS (N_DIM * K_DIM / 4 / 256)  // 16384 blocks of 256 threads
#define QUANT_BLOCKS T_TOKENS                  // 8192 blocks

using i32x4 = __attribute__((ext_vector_type(4))) int;

// ---------------------------------------------------------------------------
// Kernel 0: fused prep.
//  blocks [0, PACK_BLOCKS)              : pack int32-delivered weight -> int8
//  blocks [PACK_BLOCKS, +QUANT_BLOCKS)  : per-token dynamic quantization
// Both halves byte-identical to the previously verified kernels.
// ---------------------------------------------------------------------------
__global__ __launch_bounds__(256) void prep(const int* __restrict__ win,
                                            int8_t* __restrict__ wout,
                                            const float* __restrict__ x,
                                            int8_t* __restrict__ qx,
                                            float* __restrict__ xscale) {
    const int bid = blockIdx.x;
    const int tid = threadIdx.x;

    if (bid < PACK_BLOCKS) {
        const int idx = bid * 256 + tid;  // one dword (4 int8) out
        const i32x4 v = reinterpret_cast<const i32x4*>(win)[idx];
        uint32_t pk = (uint32_t)(v.x & 255) | ((uint32_t)(v.y & 255) << 8) |
                      ((uint32_t)(v.z & 255) << 16) | ((uint32_t)(v.w & 255) << 24);
        reinterpret_cast<int*>(wout)[idx] = (int)pk;
        return;
    }

    const int t = bid - PACK_BLOCKS;
    const float4* row = reinterpret_cast<const float4*>(x + (size_t)t * K_DIM);

    float4 v[4];
    float amax = 0.0f;
#pragma unroll
    for (int i = 0; i < 4; ++i) {
        v[i] = row[i * 256 + tid];
        amax = fmaxf(amax, fabsf(v[i].x));
        amax = fmaxf(amax, fabsf(v[i].y));
        amax = fmaxf(amax, fabsf(v[i].z));
        amax = fmaxf(amax, fabsf(v[i].w));
    }
#pragma unroll
    for (int off = 32; off > 0; off >>= 1)
        amax = fmaxf(amax, __shfl_xor(amax, off));

    __shared__ float red[4];
    if ((tid & 63) == 0) red[tid >> 6] = amax;
    __syncthreads();
    amax = fmaxf(fmaxf(red[0], red[1]), fmaxf(red[2], red[3]));

    const float scale = fmaxf(amax, 1e-30f) * (1.0f / 127.0f);
    if (tid == 0) xscale[t] = scale;

    int* qrow = reinterpret_cast<int*>(qx + (size_t)t * K_DIM);
#pragma unroll
    for (int i = 0; i < 4; ++i) {
        int q0 = (int)fminf(fmaxf(rintf(v[i].x / scale), -127.0f), 127.0f);
        int q1 = (int)fminf(fmaxf(rintf(v[i].y / scale), -127.0f), 127.0f);
        int q2 = (int)fminf(fmaxf(rintf(v[i].z / scale), -127.0f), 127.0f);
        int q3 = (int)fminf(fmaxf(rintf(v[i].w / scale), -127.0f), 127.0f);
        uint32_t pk = (uint32_t)(q0 & 255) | ((uint32_t)(q1 & 255) << 8) |
                      ((uint32_t)(q2 & 255) << 16) | ((uint32_t)(q3 & 255) << 24);
        qrow[i * 256 + tid] = (int)pk;
    }
}

// ---------------------------------------------------------------------------
// Kernel 1: int8 GEMM, 256x128 tile, BK=64, 8 waves (4M x 2N), per-wave
// output 64x64 (acc = 64 regs -> ~120 regs/wave -> 4 waves/SIMD as TWO
// independent 512-thread blocks per CU; each block's barrier drain is
// covered by the other block's MFMAs).
//
// LDS (48 KiB): [buf:2][ A: 256x64 | B: 128x64 ]  (A at +0, B at +16384).
// Same verified XOR swizzle as before (row stride 64 B):
//   staged global src col = chunk ^ (((row>>1)&3)<<4); read col likewise.
// Per K-step: {3x global_load_lds (A hi/lo + B) -> s_waitcnt vmcnt(3)
// (counted: next step's 3 stay in flight, issued one full step ahead) ->
// barrier -> 8x ds_read_b128 -> setprio(1) 16 MFMA setprio(0) -> barrier}.
//
// Fragments: A/B 16 contiguous K bytes/lane (row = base + lane&15, K-chunk
// = (lane>>4)*16).  C/D: col = lane&15, row = (lane>>4)*4 + reg.
// ---------------------------------------------------------------------------
__global__ __launch_bounds__(512, 4) void int8_gemm(const int8_t* __restrict__ qx,
                                                    const int8_t* __restrict__ w,
                                                    const float* __restrict__ xscale,
                                                    const float* __restrict__ wscale,
                                                    const float* __restrict__ bias,
                                                    float* __restrict__ out) {
    __shared__ int8_t lds[49152];

    const int tid = threadIdx.x;
    const int lane = tid & 63;
    const int wave = tid >> 6;
    const int wr = wave >> 1;  // 0..3 : 64 token rows each
    const int wn = wave & 1;   // 0..1 : 64 feature cols each
    const int l16 = lane & 15;
    const int quad = lane >> 4;

    // XCD-aware swizzle: 1024 blocks, 128 contiguous per XCD, tm-major
    // (per XCD: 4 A-panels = 4 MB -> L2-resident; B streams via LLC).
    const int bid = (int)blockIdx.x;
    const int wg = ((bid & 7) << 7) | (bid >> 3);
    const int tm = wg >> 5;  // 0..31
    const int tn = wg & 31;  // 0..31

    // staging: thread covers A rows (tid>>2), (tid>>2)+128 and B row (tid>>2),
    // 16-byte chunk (tid&3), source col pre-swizzled (linear LDS dest).
    const int s_row = tid >> 2;
    const int scol = (((tid & 3) ^ ((s_row >> 1) & 3)) << 4);
    const int fcol = ((quad ^ ((l16 >> 1) & 3)) << 4);

    const int8_t* pA = qx + (size_t)(tm * 256 + s_row) * K_DIM + scol;
    const int8_t* pB = w + (size_t)(tn * 128 + s_row) * K_DIM + scol;

    const int aoff = (wr * 64 + l16) * 64 + fcol;           // + q*1024
    const int boff = 16384 + (wn * 64 + l16) * 64 + fcol;   // + nj*1024

    i32x4 acc[4][4] = {};
    i32x4 af[4], bf[4];

#define GLOAD(gp, lp)                                              \
    __builtin_amdgcn_global_load_lds(                              \
        (const __attribute__((address_space(1))) void*)(gp),       \
        (__attribute__((address_space(3))) void*)(lp), 16, 0, 0)

#define STAGE(buf, kk)                                             \
    {                                                              \
        int8_t* l_ = lds + (buf) * 24576 + tid * 16;               \
        GLOAD(pA + (kk), l_);                                      \
        GLOAD(pA + (size_t)128 * K_DIM + (kk), l_ + 8192);         \
        GLOAD(pB + (kk), l_ + 16384);                              \
    }

#define READS(buf)                                                             \
    {                                                                          \
        const int8_t* sa_ = lds + (buf) * 24576 + aoff;                        \
        const int8_t* sb_ = lds + (buf) * 24576 + boff;                        \
        _Pragma("unroll") for (int q = 0; q < 4; ++q)                          \
            af[q] = *(const i32x4*)(sa_ + q * 1024);                           \
        _Pragma("unroll") for (int nj = 0; nj < 4; ++nj)                       \
            bf[nj] = *(const i32x4*)(sb_ + nj * 1024);                         \
    }

#define MFMAS()                                                                \
    __builtin_amdgcn_s_setprio(1);                                             \
    _Pragma("unroll") for (int q = 0; q < 4; ++q) {                            \
        _Pragma("unroll") for (int nj = 0; nj < 4; ++nj)                       \
            acc[q][nj] = __builtin_amdgcn_mfma_i32_16x16x64_i8(                \
                af[q], bf[nj], acc[q][nj], 0, 0, 0);                           \
    }                                                                          \
    __builtin_amdgcn_s_setprio(0);

    // prologue: stage K-step 0 into buf 0  (3 loads in flight)
    STAGE(0, 0)

    for (int t = 0; t < 63; ++t) {
        const int cur = t & 1;
        STAGE(cur ^ 1, (t + 1) << 6)  // +3 -> 6 outstanding
        asm volatile("s_waitcnt vmcnt(3)" ::: "memory");  // drain t's 3, keep t+1's
        __builtin_amdgcn_s_barrier();   // stage(t) visible to all waves
        READS(cur)
        MFMAS()
        __builtin_amdgcn_s_barrier();   // all reads of buf[cur] done before overwrite
    }
    // tail: t = 63, buf 1, no prefetch
    asm volatile("s_waitcnt vmcnt(0)" ::: "memory");
    __builtin_amdgcn_s_barrier();
    READS(1)
    MFMAS()

    // epilogue: dequant + bias.  C/D: col = l16, row = quad*4 + reg.
    const int rowb = tm * 256 + wr * 64 + quad * 4;
    const int colb = tn * 128 + wn * 64 + l16;
    float wsv[4], bsv[4];
#pragma unroll
    for (int nj = 0; nj < 4; ++nj) {
        wsv[nj] = wscale[colb + nj * 16];
        bsv[nj] = bias[colb + nj * 16];
    }
#pragma unroll
    for (int q = 0; q < 4; ++q) {
#pragma unroll
        for (int r = 0; r < 4; ++r) {
            const int trow = rowb + q * 16 + r;
            const float xs = xscale[trow];
            float* orow = out + (size_t)trow * N_DIM + colb;
#pragma unroll
            for (int nj = 0; nj < 4; ++nj)
                orow[nj * 16] = (float)acc[q][nj][r] * (wsv[nj] * xs) + bsv[nj];
        }
    }
#undef GLOAD
#undef STAGE
#undef READS
#undef MFMAS
}

extern "C" void kernel_launch(void* const* d_in, const int* in_sizes, int n_in,
                              void* d_out, int out_size, void* d_ws, size_t ws_size,
                              hipStream_t stream) {
    const float* x = (const float*)d_in[0];
    const int* w_i32 = (const int*)d_in[1];  // harness delivers int8 ref input as int32
    const float* wscale = (const float*)d_in[2];
    const float* bias = (const float*)d_in[3];
    float* out = (float*)d_out;

    // workspace: qx (32 MB) | xscale (32 KB pad to 64 KB) | packed weight (16 MB)
    int8_t* qx = (int8_t*)d_ws;
    float* xscale = (float*)((char*)d_ws + (size_t)T_TOKENS * K_DIM);
    int8_t* wpk = (int8_t*)((char*)d_ws + (size_t)T_TOKENS * K_DIM + 65536);

    prep<<<PACK_BLOCKS + QUANT_BLOCKS, 256, 0, stream>>>(w_i32, wpk, x, qx, xscale);

    int8_gemm<<<dim3(1024), dim3(512), 0, stream>>>(qx, wpk, xscale, wscale, bias, out);
}